// Round 10
// baseline (114.376 us; speedup 1.0000x reference)
//
#include <hip/hip_runtime.h>

#define NDIM 28
#define SPAT 784            // 28*28
#define STRIPS 196          // float4 strips per plane
#define NB 256
#define CIN 256
#define COUT 256
#define SCH 4               // Cin split factor
#define CPC (CIN / SCH)     // 64 planes per chunk
#define XSC 36              // LDS halo'd plane row stride (floats)
#define QB 64               // batches per pipeline quarter

typedef float f4v __attribute__((ext_vector_type(4)));

// ---- body of R6's k_sum (proven at read ceiling 7.04 TB/s) ----
__device__ __forceinline__ void dev_sum(const float* __restrict__ x,
                                        float* __restrict__ pbuf,
                                        int b, int chunk, int t) {
    if (t >= STRIPS) return;
    const float4* xp = (const float4*)x
        + ((size_t)b * CIN + (size_t)chunk * CPC) * STRIPS + t;
    float ax = 0.f, ay = 0.f, az = 0.f, aw = 0.f;
    #pragma unroll 16
    for (int c = 0; c < CPC; ++c) {
        float4 v = xp[c * STRIPS];
        ax += v.x; ay += v.y; az += v.z; aw += v.w;
    }
    ((float4*)pbuf)[((size_t)b * SCH + chunk) * STRIPS + t] = make_float4(ax, ay, az, aw);
}

// ---- conv body: IDENTICAL to R9 except store flavor = sc1 (device-scope,
// no nt): bypass L2 allocate (R8's thrash) but allow LLC write-combining
// (nt's suspected 64B row-thrash). Single-variable A/B. ----
__device__ __forceinline__ void dev_conv(const float* __restrict__ pbuf,
                                         const float* __restrict__ w,
                                         float* __restrict__ out,
                                         float* xs, int b, int cg, int t) {
    if (t < STRIPS) {
        const float4* pp = (const float4*)pbuf + (size_t)b * SCH * STRIPS + t;
        float4 a = pp[0];
        #pragma unroll
        for (int c = 1; c < SCH; ++c) {
            float4 v = pp[c * STRIPS];
            a.x += v.x; a.y += v.y; a.z += v.z; a.w += v.w;
        }
        int i = t / 7, q = t % 7;
        *(float4*)&xs[i * XSC + q * 4] = a;
        if (q == 0)                          // col halo
            *(float4*)&xs[i * XSC + 28] = a;
        if (i < 2) {                         // row halo
            *(float4*)&xs[(i + 28) * XSC + q * 4] = a;
            if (q == 0)
                *(float4*)&xs[(i + 28) * XSC + 28] = a;
        }
    }
    __syncthreads();

    if (t >= STRIPS) return;
    int i  = t / 7;
    int js = (t % 7) * 4;

    float W[3][8];
    #pragma unroll
    for (int a = 0; a < 3; ++a) {
        float4 lo = *(const float4*)&xs[(i + a) * XSC + js];
        float4 hi = *(const float4*)&xs[(i + a) * XSC + js + 4];
        W[a][0] = lo.x; W[a][1] = lo.y; W[a][2] = lo.z; W[a][3] = lo.w;
        W[a][4] = hi.x; W[a][5] = hi.y; W[a][6] = hi.z; W[a][7] = hi.w;
    }

    size_t ob = ((size_t)b * COUT + (size_t)cg * 64) * SPAT + i * NDIM + js;

    #pragma unroll 4
    for (int cl = 0; cl < 64; ++cl) {
        const float* wp = w + (size_t)(cg * 64 + cl) * (CIN * 9);
        float o0 = 0.f, o1 = 0.f, o2 = 0.f, o3 = 0.f;
        #pragma unroll
        for (int a = 0; a < 3; ++a) {
            #pragma unroll
            for (int c = 0; c < 3; ++c) {
                float fv = wp[8 - 3 * a - c];   // w0[co, 2-a, 2-c]
                o0 += fv * W[a][0 + c];
                o1 += fv * W[a][1 + c];
                o2 += fv * W[a][2 + c];
                o3 += fv * W[a][3 + c];
            }
        }
        f4v o = {o0, o1, o2, o3};
        float* addr = out + ob + (size_t)cl * SPAT;
        asm volatile("global_store_dwordx4 %0, %1, off sc1"
                     :: "v"(addr), "v"(o) : "memory");
    }
}

// quarter sum: 256 blocks, b = b0 + bid>>2, chunk = bid&3
__global__ __launch_bounds__(256) void k_sumq(const float* __restrict__ x,
                                              float* __restrict__ pbuf, int b0) {
    dev_sum(x, pbuf, b0 + (blockIdx.x >> 2), blockIdx.x & 3, threadIdx.x);
}

// quarter conv: 256 blocks
__global__ __launch_bounds__(256) void k_convq(const float* __restrict__ pbuf,
                                               const float* __restrict__ w,
                                               float* __restrict__ out, int b0) {
    __shared__ float xs[30 * XSC];
    dev_conv(pbuf, w, out, xs, b0 + (blockIdx.x >> 2), blockIdx.x & 3, threadIdx.x);
}

// mixed: blocks 0..255 conv quarter bc0 (long pole first), 256..511 sum quarter bs0
__global__ __launch_bounds__(256) void k_mix(const float* __restrict__ x,
                                             float* __restrict__ pbuf,
                                             const float* __restrict__ w,
                                             float* __restrict__ out,
                                             int bs0, int bc0) {
    __shared__ float xs[30 * XSC];
    int bid = blockIdx.x;
    if (bid < 256) {
        dev_conv(pbuf, w, out, xs, bc0 + (bid >> 2), bid & 3, threadIdx.x);
    } else {
        bid -= 256;
        dev_sum(x, pbuf, bs0 + (bid >> 2), bid & 3, threadIdx.x);
    }
}

extern "C" void kernel_launch(void* const* d_in, const int* in_sizes, int n_in,
                              void* d_out, int out_size, void* d_ws, size_t ws_size,
                              hipStream_t stream) {
    const float* x = (const float*)d_in[0];       // (256,256,28,28) f32
    const float* w = (const float*)d_in[1];       // (256,256,3,3) f32
    float* out = (float*)d_out;                   // (256,256,28,28) f32
    float* pbuf = (float*)d_ws;                   // 256*4*784 f32 = 3.2 MB

    // Software pipeline over batch quarters: overlap conv(q) writes with sum(q+1) reads.
    k_sumq <<<256, 256, 0, stream>>>(x, pbuf, 0);
    k_mix  <<<512, 256, 0, stream>>>(x, pbuf, w, out, 1 * QB, 0 * QB);
    k_mix  <<<512, 256, 0, stream>>>(x, pbuf, w, out, 2 * QB, 1 * QB);
    k_mix  <<<512, 256, 0, stream>>>(x, pbuf, w, out, 3 * QB, 2 * QB);
    k_convq<<<256, 256, 0, stream>>>(pbuf, w, out, 3 * QB);
}

// Round 11
// 74.235 us; speedup vs baseline: 1.5407x; 1.5407x over previous
//
#include <hip/hip_runtime.h>

#define NDIM 28
#define SPAT 784            // 28*28
#define STRIPS 196          // float4 strips per plane
#define NB 256
#define CIN 256
#define COUT 256
#define SCH 4               // Cin split factor
#define CPC (CIN / SCH)     // 64 planes per chunk
#define XSC 36              // LDS halo'd plane row stride (floats)

typedef float f4v __attribute__((ext_vector_type(4)));

// Kernel 1 (IDENTICAL to R6, proven 7.04 TB/s): block = (b, chunk), 1024 blocks.
__global__ __launch_bounds__(256) void k_sum(const float* __restrict__ x,
                                             float* __restrict__ pbuf) {
    int bid = blockIdx.x;          // 0..1023
    int b     = bid >> 2;
    int chunk = bid & 3;
    int t = threadIdx.x;
    if (t >= STRIPS) return;

    const float4* xp = (const float4*)x
        + ((size_t)b * CIN + (size_t)chunk * CPC) * STRIPS + t;
    float ax = 0.f, ay = 0.f, az = 0.f, aw = 0.f;
    #pragma unroll 16
    for (int c = 0; c < CPC; ++c) {
        float4 v = xp[c * STRIPS];
        ax += v.x; ay += v.y; az += v.z; aw += v.w;
    }
    ((float4*)pbuf)[((size_t)b * SCH + chunk) * STRIPS + t] = make_float4(ax, ay, az, aw);
}

// Kernel 2: ONE block per batch b (256 blocks = 1/CU). Block computes ALL 256
// co planes -> each CU emits a single strictly-linear 803 KB nt write sweep.
// Tests the write-stream-locality theory for the 4.3 TB/s nt cap.
__global__ __launch_bounds__(256) void k_conv256(const float* __restrict__ pbuf,
                                                 const float* __restrict__ w,
                                                 float* __restrict__ out) {
    __shared__ float xs[30 * XSC];

    int b = blockIdx.x;
    int t = threadIdx.x;

    if (t < STRIPS) {
        const float4* pp = (const float4*)pbuf + (size_t)b * SCH * STRIPS + t;
        float4 a = pp[0];
        #pragma unroll
        for (int c = 1; c < SCH; ++c) {
            float4 v = pp[c * STRIPS];
            a.x += v.x; a.y += v.y; a.z += v.z; a.w += v.w;
        }
        int i = t / 7, q = t % 7;
        *(float4*)&xs[i * XSC + q * 4] = a;
        if (q == 0)                          // col halo: cols 28,29 = cols 0,1
            *(float4*)&xs[i * XSC + 28] = a;
        if (i < 2) {                         // row halo: rows 28,29 = rows 0,1
            *(float4*)&xs[(i + 28) * XSC + q * 4] = a;
            if (q == 0)
                *(float4*)&xs[(i + 28) * XSC + 28] = a;
        }
    }
    __syncthreads();

    if (t >= STRIPS) return;
    int i  = t / 7;
    int js = (t % 7) * 4;

    float W[3][8];
    #pragma unroll
    for (int a = 0; a < 3; ++a) {
        float4 lo = *(const float4*)&xs[(i + a) * XSC + js];
        float4 hi = *(const float4*)&xs[(i + a) * XSC + js + 4];
        W[a][0] = lo.x; W[a][1] = lo.y; W[a][2] = lo.z; W[a][3] = lo.w;
        W[a][4] = hi.x; W[a][5] = hi.y; W[a][6] = hi.z; W[a][7] = hi.w;
    }

    size_t ob = (size_t)b * COUT * SPAT + i * NDIM + js;

    #pragma unroll 4
    for (int cl = 0; cl < 256; ++cl) {
        const float* wp = w + (size_t)cl * (CIN * 9);   // kernel[cl,0,:,:], block-uniform
        float o0 = 0.f, o1 = 0.f, o2 = 0.f, o3 = 0.f;
        #pragma unroll
        for (int a = 0; a < 3; ++a) {
            #pragma unroll
            for (int c = 0; c < 3; ++c) {
                float fv = wp[8 - 3 * a - c];   // w0[cl, 2-a, 2-c]
                o0 += fv * W[a][0 + c];
                o1 += fv * W[a][1 + c];
                o2 += fv * W[a][2 + c];
                o3 += fv * W[a][3 + c];
            }
        }
        f4v o = {o0, o1, o2, o3};
        __builtin_nontemporal_store(o, (f4v*)(out + ob + (size_t)cl * SPAT));
    }
}

extern "C" void kernel_launch(void* const* d_in, const int* in_sizes, int n_in,
                              void* d_out, int out_size, void* d_ws, size_t ws_size,
                              hipStream_t stream) {
    const float* x = (const float*)d_in[0];       // (256,256,28,28) f32
    const float* w = (const float*)d_in[1];       // (256,256,3,3) f32
    float* out = (float*)d_out;                   // (256,256,28,28) f32
    float* pbuf = (float*)d_ws;                   // 256*4*784 f32 = 3.2 MB

    k_sum    <<<NB * SCH, 256, 0, stream>>>(x, pbuf);   // 1024 blocks, 4/CU
    k_conv256<<<NB,       256, 0, stream>>>(pbuf, w, out); // 256 blocks, 1/CU, linear sweep
}